// Round 12
// baseline (873.296 us; speedup 1.0000x reference)
//
#include <hip/hip_runtime.h>
#include <hip/hip_cooperative_groups.h>

namespace cg = cooperative_groups;

// ---------------------------------------------------------------------------
// InterpretableFusion v12 — ONE cooperative kernel, 3 phases, grid.sync.
//   scores[n,m] = ( x.(G_m l) + x.v_m + l.u_m + c_m )/sqrt(D)
// v11 -> v12 (the swap): store Gt_m = G_m^T in phase 1; phase 2 computes
// y = x Gt_m^T via MFMA with the X tile as A-operand (staged ONCE per tile),
// and s = (y+u).l with l loaded straight from global into registers, issued
// before the MFMA k-loop (latency hidden under 16 k-steps). Eliminates all
// per-m LDS staging (v11's dominant serial stall: stage->barrier->compute,
// ~900cy exposed x4m x1563 tiles). Live regs ~80 -> launch_bounds(512,4)
// (128 unified cap incl. AGPRs) -> 2 blocks/CU co-resident.
// Phase 1: Gt (512 subtiles) + u,v,c + flags -> out scratch (unchanged idx)
// Phase 2: per 32-row tile: stage X once; 4m x {l->regs, MFMA y, dot,
//          reduce, exp} -> weights. Writes ONLY weights region.
// Phase 3: fused = sum_m w_m L_m (flat coalesced walk, proven v9/v11).
// ---------------------------------------------------------------------------

typedef __bf16 bf16x8 __attribute__((ext_vector_type(8)));
typedef __bf16 bf16x4 __attribute__((ext_vector_type(4)));
typedef float  f32x4  __attribute__((ext_vector_type(4)));

#define NTOK 50000
#define DDIM 512
#define NMOD 4
#define BN   32
#define NBLK ((NTOK + BN - 1) / BN)        // 1563
#define WOFF ((size_t)NTOK * DDIM)         // weights region (float offset)
#define UOFF 600000                        // u[m][d']  (l-side)
#define VOFF 610000                        // v[m][d]   (x-side)
#define COFF 620000                        // c[m]
#define FOFF 620004                        // 32 bias-nonzero flags
#define SCALE 0.044194173824159216f        // 1/sqrt(512)

// row stride 1024B (512 bf16); XOR byte bits 4-6 with row&7 (guide §6 G4)
#define SWZ(r, b) ((((r) * 1024) + (b)) ^ (((r) & 7) << 4))

__global__ __launch_bounds__(512, 4) void mono_kernel(
    const float* __restrict__ gnn, const float* __restrict__ lat,
    const float* __restrict__ Wq, const float* __restrict__ bq,
    const float* __restrict__ Wk, const float* __restrict__ bk,
    float* __restrict__ out)
{
    __shared__ __align__(16) char smem[34816];   // 32K tile + reductions
    const int tid = threadIdx.x;
    const int bid = blockIdx.x;
    const int ngrid = gridDim.x;
    cg::grid_group gg = cg::this_grid();

    // ===== phase 1: Gt[m][e][d] = sum_r Wk[m][r][e] * Wq[r][d]  (+ u,v,c) ====
    {
        float* ldsA = (float*)smem;            // [r][64 e-cols of Wk_m]
        float* ldsB = (float*)(smem + 16384);  // [r][32 d-cols of Wq]
        for (int gb = bid; gb < 512; gb += ngrid) {
            const int m = gb >> 7, ib = gb & 127, eblk = ib >> 4, dpb = ib & 15;
            const int el = tid >> 3, c8 = tid & 7;
            f32x4 ac = {0.f, 0.f, 0.f, 0.f};
            for (int r0 = 0; r0 < DDIM; r0 += 64) {
                __syncthreads();
                #pragma unroll
                for (int it = 0; it < 2; ++it) {
                    int idx = it * 512 + tid, r = idx >> 4, c4 = idx & 15;
                    *(f32x4*)&ldsA[r * 64 + c4 * 4] =
                        *(const f32x4*)&Wk[((size_t)m * DDIM + r0 + r) * DDIM + eblk * 64 + c4 * 4];
                }
                {
                    int r = tid >> 3, c4 = tid & 7;
                    *(f32x4*)&ldsB[r * 32 + c4 * 4] =
                        *(const f32x4*)&Wq[(size_t)(r0 + r) * DDIM + dpb * 32 + c4 * 4];
                }
                __syncthreads();
                for (int r = 0; r < 64; ++r) {
                    float wk = ldsA[r * 64 + el];
                    ac += wk * *(const f32x4*)&ldsB[r * 32 + c8 * 4];
                }
            }
            __bf16* Gw = (__bf16*)out;
            bf16x4 o;
            o[0] = (__bf16)ac[0]; o[1] = (__bf16)ac[1];
            o[2] = (__bf16)ac[2]; o[3] = (__bf16)ac[3];
            *(bf16x4*)(Gw + ((size_t)m * DDIM + eblk * 64 + el) * DDIM
                       + dpb * 32 + c8 * 4) = o;
        }

        if (bid < 32) {                        // u, v, c + bias flags
            __syncthreads();                   // own block's LDS reads done
            float* up = (float*)smem;          // [4][64]
            float* vp = (float*)smem + 256;    // [4][64]
            const int m2 = bid >> 3, dc = bid & 7;
            if (tid < 256) {
                const int dl2 = tid & 63, eg = tid >> 6;
                const int d = dc * 64 + dl2;
                float us = 0.f, vs = 0.f;
                #pragma unroll 4
                for (int e = eg * 128; e < eg * 128 + 128; ++e) {
                    us += Wk[((size_t)m2 * DDIM + e) * DDIM + d] * bq[e];
                    vs += Wq[(size_t)e * DDIM + d] * bk[m2 * DDIM + e];
                }
                up[eg * 64 + dl2] = us; vp[eg * 64 + dl2] = vs;
            }
            __syncthreads();
            if (tid < 64) {
                const int d = dc * 64 + tid;
                float uu = up[tid] + up[64+tid] + up[128+tid] + up[192+tid];
                float vv = vp[tid] + vp[64+tid] + vp[128+tid] + vp[192+tid];
                out[UOFF + m2 * DDIM + d] = uu;
                out[VOFF + m2 * DDIM + d] = vv;
                float cp = 0.f;
                if (dc == 0) {
                    #pragma unroll
                    for (int i = 0; i < 8; ++i)
                        cp += bq[tid * 8 + i] * bk[m2 * DDIM + tid * 8 + i];
                    #pragma unroll
                    for (int msk = 1; msk < 64; msk <<= 1)
                        cp += __shfl_xor(cp, msk, 64);
                    if (tid == 0) out[COFF + m2] = cp;
                }
                unsigned long long anyb =
                    __ballot((uu != 0.f) || (vv != 0.f) || (cp != 0.f));
                if (tid == 0) out[FOFF + bid] = anyb ? 1.f : 0.f;  // always written
            }
        }
    }
    gg.sync();   // Gt/u/v/c/flags visible device-wide

    // ===== phase 2: scores -> softmax -> weights (no per-m staging) =====
    {
        __bf16* tile  = (__bf16*)smem;             // 32 KiB: X tile only
        float* s_part = (float*)(smem + 32768);    // [8][32]
        float* s_all  = (float*)(smem + 33792);    // [32][4]
        const __bf16* Gb = (const __bf16*)out;
        const int lane = tid & 63, w = tid >> 6;
        const int g = (lane >> 4) & 3, c = lane & 15;

        bool bias = false;
        for (int i2 = 0; i2 < 32; ++i2) bias |= (out[FOFF + i2] != 0.f);
        float cm[4];
        #pragma unroll
        for (int m = 0; m < 4; ++m) cm[m] = out[COFF + m];

        for (int t = bid; t < NBLK; t += ngrid) {
            const int row0 = t * BN;
            const int vrows = (NTOK - row0 < BN) ? (NTOK - row0) : BN;

            // stage X once per tile (8 f32x4 nt loads -> bf16 swizzled LDS)
            {
                const float* src = gnn + (size_t)row0 * DDIM;
                #pragma unroll
                for (int i = 0; i < 8; ++i) {
                    int f4 = i * 512 + tid, r = f4 >> 7, c4 = f4 & 127;
                    f32x4 v = (r < vrows)
                        ? __builtin_nontemporal_load(
                              (const f32x4*)(src + (size_t)r * DDIM + c4 * 4))
                        : (f32x4){0.f, 0.f, 0.f, 0.f};
                    bf16x4 o;
                    o[0] = (__bf16)v[0]; o[1] = (__bf16)v[1];
                    o[2] = (__bf16)v[2]; o[3] = (__bf16)v[3];
                    *(bf16x4*)((char*)tile + SWZ(r, c4 * 8)) = o;
                }
            }
            __syncthreads();

            for (int m = 0; m < NMOD; ++m) {
                float p[2][4];
                if (bias) {
                    // x.v part: read x scalars from tile (x IS resident)
                    float v4[4];
                    #pragma unroll
                    for (int j = 0; j < 4; ++j)
                        v4[j] = out[VOFF + m * DDIM + w * 64 + j * 16 + c];
                    #pragma unroll
                    for (int rt = 0; rt < 2; ++rt)
                        #pragma unroll
                        for (int reg = 0; reg < 4; ++reg) {
                            int r = rt * 16 + g * 4 + reg;
                            float tacc = 0.f;
                            #pragma unroll
                            for (int j = 0; j < 4; ++j) {
                                int col = w * 64 + j * 16 + c;
                                float xv = (float)*(const __bf16*)((const char*)tile +
                                                                   SWZ(r, col * 2));
                                tacc += xv * v4[j];
                            }
                            p[rt][reg] = tacc;
                        }
                } else {
                    #pragma unroll
                    for (int rt = 0; rt < 2; ++rt)
                        #pragma unroll
                        for (int reg = 0; reg < 4; ++reg)
                            p[rt][reg] = 0.f;
                }

                const __bf16* Gm = Gb + (size_t)m * DDIM * DDIM;
                #pragma unroll
                for (int jh = 0; jh < 2; ++jh) {
                    // issue l loads FIRST (latency hides under the MFMA k-loop)
                    float lv[2][2][4];
                    #pragma unroll
                    for (int rt = 0; rt < 2; ++rt)
                        #pragma unroll
                        for (int jj = 0; jj < 2; ++jj)
                            #pragma unroll
                            for (int reg = 0; reg < 4; ++reg) {
                                int r = rt * 16 + g * 4 + reg;
                                int row = row0 + r;
                                int e = w * 64 + (jh * 2 + jj) * 16 + c;
                                lv[rt][jj][reg] = (row < NTOK)
                                    ? __builtin_nontemporal_load(
                                          lat + ((size_t)row * NMOD + m) * DDIM + e)
                                    : 0.f;
                            }

                    f32x4 kacc[2][2];
                    #pragma unroll
                    for (int rt = 0; rt < 2; ++rt) {
                        kacc[rt][0] = (f32x4){0.f, 0.f, 0.f, 0.f};
                        kacc[rt][1] = (f32x4){0.f, 0.f, 0.f, 0.f};
                    }
                    const __bf16* gp0 = Gm + (size_t)(w * 64 + (jh * 2 + 0) * 16 + c) * DDIM + g * 8;
                    const __bf16* gp1 = Gm + (size_t)(w * 64 + (jh * 2 + 1) * 16 + c) * DDIM + g * 8;
                    #pragma unroll 2
                    for (int k0 = 0; k0 < DDIM; k0 += 32) {
                        bf16x8 b0 = *(const bf16x8*)(gp0 + k0);
                        bf16x8 b1 = *(const bf16x8*)(gp1 + k0);
                        bf16x8 a[2];
                        const int kb = k0 * 2 + g * 16;
                        #pragma unroll
                        for (int rt = 0; rt < 2; ++rt)
                            a[rt] = *(const bf16x8*)((const char*)tile +
                                                     SWZ(rt * 16 + c, kb));
                        #pragma unroll
                        for (int rt = 0; rt < 2; ++rt) {
                            kacc[rt][0] = __builtin_amdgcn_mfma_f32_16x16x32_bf16(
                                a[rt], b0, kacc[rt][0], 0, 0, 0);
                            kacc[rt][1] = __builtin_amdgcn_mfma_f32_16x16x32_bf16(
                                a[rt], b1, kacc[rt][1], 0, 0, 0);
                        }
                    }

                    // s += (y + u) . l   (u = 0 fast path)
                    float u0 = 0.f, u1 = 0.f;
                    if (bias) {
                        u0 = out[UOFF + m * DDIM + w * 64 + (jh * 2 + 0) * 16 + c];
                        u1 = out[UOFF + m * DDIM + w * 64 + (jh * 2 + 1) * 16 + c];
                    }
                    #pragma unroll
                    for (int rt = 0; rt < 2; ++rt)
                        #pragma unroll
                        for (int reg = 0; reg < 4; ++reg)
                            p[rt][reg] += lv[rt][0][reg] * (kacc[rt][0][reg] + u0)
                                        + lv[rt][1][reg] * (kacc[rt][1][reg] + u1);
                    __builtin_amdgcn_sched_barrier(0);
                }

                // reduce over the 16 c-lanes (e-cols), then across 8 waves
                #pragma unroll
                for (int msk = 1; msk < 16; msk <<= 1)
                    #pragma unroll
                    for (int rt = 0; rt < 2; ++rt)
                        #pragma unroll
                        for (int reg = 0; reg < 4; ++reg)
                            p[rt][reg] += __shfl_xor(p[rt][reg], msk, 64);
                if (c == 0) {
                    #pragma unroll
                    for (int rt = 0; rt < 2; ++rt)
                        #pragma unroll
                        for (int reg = 0; reg < 4; ++reg)
                            s_part[w * 32 + rt * 16 + g * 4 + reg] = p[rt][reg];
                }
                __syncthreads();                 // B1: s_part complete
                if (tid < BN) {
                    float s = 0.f;
                    #pragma unroll
                    for (int ww = 0; ww < 8; ++ww) s += s_part[ww * 32 + tid];
                    s_all[tid * 4 + m] = s + cm[m];
                }
                __syncthreads();                 // B2: s_part reads done
            }

            if (tid < BN && row0 + tid < NTOK) {
                float e0 = __expf(s_all[tid*4+0] * SCALE), e1 = __expf(s_all[tid*4+1] * SCALE),
                      e2 = __expf(s_all[tid*4+2] * SCALE), e3 = __expf(s_all[tid*4+3] * SCALE);
                float iz = 1.f / (e0 + e1 + e2 + e3);
                f32x4 wv = {e0 * iz, e1 * iz, e2 * iz, e3 * iz};
                *(f32x4*)(out + WOFF + (size_t)(row0 + tid) * 4) = wv;
            }
            __syncthreads();   // tile reads (incl. bias path) done before restage
        }
    }
    gg.sync();   // weights visible; Gt/u/v/c/flags region now dead

    // ===== phase 3: fused = sum_m w_m L_m (flat coalesced walk) =====
    {
        const long total4 = (long)NTOK * (DDIM / 4);          // 6,400,000
        for (long idx = (long)bid * 512 + tid; idx < total4;
             idx += (long)ngrid * 512) {
            const int row = (int)(idx >> 7), c4 = (int)(idx & 127);
            f32x4 w4 = *(const f32x4*)(out + WOFF + (size_t)row * 4);
            f32x4 acc = {0.f, 0.f, 0.f, 0.f};
            #pragma unroll
            for (int m = 0; m < NMOD; ++m) {
                f32x4 v = __builtin_nontemporal_load(
                    (const f32x4*)(lat + ((size_t)row * NMOD + m) * DDIM + c4 * 4));
                acc += w4[m] * v;
            }
            __builtin_nontemporal_store(acc, (f32x4*)(out + (size_t)idx * 4));
        }
    }
}

extern "C" void kernel_launch(void* const* d_in, const int* in_sizes, int n_in,
                              void* d_out, int out_size, void* d_ws, size_t ws_size,
                              hipStream_t stream)
{
    const float* gnn = (const float*)d_in[0];   // [N, D]
    const float* lat = (const float*)d_in[1];   // [N, M, D]
    const float* Wq  = (const float*)d_in[2];   // [D, D]
    const float* bq  = (const float*)d_in[3];   // [D]
    const float* Wk  = (const float*)d_in[4];   // [M, D, D]
    const float* bk  = (const float*)d_in[5];   // [M, D]
    float* out = (float*)d_out;                 // fused [N,D] ++ weights [N,M]

    int maxb = 0;
    hipError_t oe = hipOccupancyMaxActiveBlocksPerMultiprocessor(
        &maxb, mono_kernel, 512, 0);
    const int ngrid = (oe == hipSuccess && maxb >= 2) ? 512 : 256;

    void* args[] = { (void*)&gnn, (void*)&lat, (void*)&Wq, (void*)&bq,
                     (void*)&Wk, (void*)&bk, (void*)&out };
    hipLaunchCooperativeKernel((const void*)mono_kernel, dim3(ngrid), dim3(512),
                               args, 0, stream);
}

// Round 13
// 697.302 us; speedup vs baseline: 1.2524x; 1.2524x over previous
//
#include <hip/hip_runtime.h>
#include <hip/hip_cooperative_groups.h>

namespace cg = cooperative_groups;

// ---------------------------------------------------------------------------
// InterpretableFusion v13 — ONE cooperative kernel, 3 phases, grid.sync.
//   scores[n,m] = ( x.(G_m l) + x.v_m + l.u_m + c_m )/sqrt(D)
//   y = x Gt_m^T via MFMA (X tile staged once), s = (y+u).l with l from global.
// v12 -> v13:
//  (1) PACKED-G fragment layout: phase 1 stores Gt in MFMA b-fragment order
//      Gpack[m][kk][eta][lane] (16B units) so each b-load is one contiguous
//      1KB wave read (was: 64 scattered 16B reads at 1KB stride, on the MFMA
//      critical path — the reason MfmaUtil never exceeded ~6%).
//  (2) fit the 64-arch-VGPR cap of launch_bounds(512,4) honestly:
//      lv loads AFTER the k-loop, folded 8-at-a-time; sm[] in registers;
//      s_part double-buffered -> 6 barriers/tile (was 10). v12's preloaded
//      lv[16] overflowed the cap -> 150MB spill traffic -> 873us.
// Phase 1: packed Gt + u,v,c + flags -> out scratch. Phase 3: flat fuse walk.
// ---------------------------------------------------------------------------

typedef __bf16 bf16x8 __attribute__((ext_vector_type(8)));
typedef __bf16 bf16x4 __attribute__((ext_vector_type(4)));
typedef float  f32x4  __attribute__((ext_vector_type(4)));

#define NTOK 50000
#define DDIM 512
#define NMOD 4
#define BN   32
#define NBLK ((NTOK + BN - 1) / BN)        // 1563
#define WOFF ((size_t)NTOK * DDIM)         // weights region (float offset)
#define UOFF 600000                        // u[m][d']  (l-side)
#define VOFF 610000                        // v[m][d]   (x-side)
#define COFF 620000                        // c[m]
#define FOFF 620004                        // 32 bias-nonzero flags
#define SCALE 0.044194173824159216f        // 1/sqrt(512)

// X-tile swizzle: row stride 1024B; XOR byte bits 4-6 with row&7 (guide §6 G4)
#define SWZ(r, b) ((((r) * 1024) + (b)) ^ (((r) & 7) << 4))

__global__ __launch_bounds__(512, 4) void mono_kernel(
    const float* __restrict__ gnn, const float* __restrict__ lat,
    const float* __restrict__ Wq, const float* __restrict__ bq,
    const float* __restrict__ Wk, const float* __restrict__ bk,
    float* __restrict__ out)
{
    __shared__ __align__(16) char smem[34816];   // 32K tile + 2K s_part dbuf
    const int tid = threadIdx.x;
    const int bid = blockIdx.x;
    const int ngrid = gridDim.x;
    cg::grid_group gg = cg::this_grid();

    // ===== phase 1: Gt[m][e][d] = sum_r Wk[m][r][e]*Wq[r][d], PACKED store ===
    {
        float* ldsA = (float*)smem;            // [r][64 e-cols of Wk_m]
        float* ldsB = (float*)(smem + 16384);  // [r][32 d-cols of Wq]
        for (int gb = bid; gb < 512; gb += ngrid) {
            const int m = gb >> 7, ib = gb & 127, eblk = ib >> 4, dpb = ib & 15;
            const int el = tid >> 3, c8 = tid & 7;
            f32x4 ac = {0.f, 0.f, 0.f, 0.f};
            for (int r0 = 0; r0 < DDIM; r0 += 64) {
                __syncthreads();
                #pragma unroll
                for (int it = 0; it < 2; ++it) {
                    int idx = it * 512 + tid, r = idx >> 4, c4 = idx & 15;
                    *(f32x4*)&ldsA[r * 64 + c4 * 4] =
                        *(const f32x4*)&Wk[((size_t)m * DDIM + r0 + r) * DDIM + eblk * 64 + c4 * 4];
                }
                {
                    int r = tid >> 3, c4 = tid & 7;
                    *(f32x4*)&ldsB[r * 32 + c4 * 4] =
                        *(const f32x4*)&Wq[(size_t)(r0 + r) * DDIM + dpb * 32 + c4 * 4];
                }
                __syncthreads();
                for (int r = 0; r < 64; ++r) {
                    float wk = ldsA[r * 64 + el];
                    ac += wk * *(const f32x4*)&ldsB[r * 32 + c8 * 4];
                }
            }
            // packed store: element (e,d): kk=d>>5, g=(d>>3)&3, eta=e>>4,
            // lane = g*16+(e&15); 16B-unit = ((m*16+kk)*32+eta)*64+lane
            __bf16* Gw = (__bf16*)out;
            const int eta = eblk * 4 + (el >> 4);
            const int lam = (c8 >> 1) * 16 + (el & 15);
            size_t abf = ((((size_t)m * 16 + dpb) * 32 + eta) * 64 + lam) * 8
                         + (c8 & 1) * 4;
            bf16x4 o;
            o[0] = (__bf16)ac[0]; o[1] = (__bf16)ac[1];
            o[2] = (__bf16)ac[2]; o[3] = (__bf16)ac[3];
            *(bf16x4*)(Gw + abf) = o;
        }

        if (bid < 32) {                        // u, v, c + bias flags
            __syncthreads();                   // own block's LDS reads done
            float* up = (float*)smem;          // [4][64]
            float* vp = (float*)smem + 256;    // [4][64]
            const int m2 = bid >> 3, dc = bid & 7;
            if (tid < 256) {
                const int dl2 = tid & 63, eg = tid >> 6;
                const int d = dc * 64 + dl2;
                float us = 0.f, vs = 0.f;
                #pragma unroll 4
                for (int e = eg * 128; e < eg * 128 + 128; ++e) {
                    us += Wk[((size_t)m2 * DDIM + e) * DDIM + d] * bq[e];
                    vs += Wq[(size_t)e * DDIM + d] * bk[m2 * DDIM + e];
                }
                up[eg * 64 + dl2] = us; vp[eg * 64 + dl2] = vs;
            }
            __syncthreads();
            if (tid < 64) {
                const int d = dc * 64 + tid;
                float uu = up[tid] + up[64+tid] + up[128+tid] + up[192+tid];
                float vv = vp[tid] + vp[64+tid] + vp[128+tid] + vp[192+tid];
                out[UOFF + m2 * DDIM + d] = uu;
                out[VOFF + m2 * DDIM + d] = vv;
                float cp = 0.f;
                if (dc == 0) {
                    #pragma unroll
                    for (int i = 0; i < 8; ++i)
                        cp += bq[tid * 8 + i] * bk[m2 * DDIM + tid * 8 + i];
                    #pragma unroll
                    for (int msk = 1; msk < 64; msk <<= 1)
                        cp += __shfl_xor(cp, msk, 64);
                    if (tid == 0) out[COFF + m2] = cp;
                }
                unsigned long long anyb =
                    __ballot((uu != 0.f) || (vv != 0.f) || (cp != 0.f));
                if (tid == 0) out[FOFF + bid] = anyb ? 1.f : 0.f;  // always written
            }
        }
    }
    gg.sync();   // packed Gt/u/v/c/flags visible device-wide

    // ===== phase 2: scores -> softmax -> weights =====
    {
        __bf16* tile  = (__bf16*)smem;             // 32 KiB: X tile
        float* s_part = (float*)(smem + 32768);    // 2 x [8][32] double buffer
        const __bf16* Gp = (const __bf16*)out;
        const int lane = tid & 63, w = tid >> 6;
        const int g = (lane >> 4) & 3, c = lane & 15;

        bool bias = false;
        for (int i2 = 0; i2 < 32; ++i2) bias |= (out[FOFF + i2] != 0.f);
        float cm[4];
        #pragma unroll
        for (int m = 0; m < 4; ++m) cm[m] = out[COFF + m];

        for (int t = bid; t < NBLK; t += ngrid) {
            const int row0 = t * BN;
            const int vrows = (NTOK - row0 < BN) ? (NTOK - row0) : BN;

            {   // stage X once per tile
                const float* src = gnn + (size_t)row0 * DDIM;
                #pragma unroll
                for (int i = 0; i < 8; ++i) {
                    int f4 = i * 512 + tid, r = f4 >> 7, c4 = f4 & 127;
                    f32x4 v = (r < vrows)
                        ? __builtin_nontemporal_load(
                              (const f32x4*)(src + (size_t)r * DDIM + c4 * 4))
                        : (f32x4){0.f, 0.f, 0.f, 0.f};
                    bf16x4 o;
                    o[0] = (__bf16)v[0]; o[1] = (__bf16)v[1];
                    o[2] = (__bf16)v[2]; o[3] = (__bf16)v[3];
                    *(bf16x4*)((char*)tile + SWZ(r, c4 * 8)) = o;
                }
            }
            __syncthreads();

            float sm[4];   // per-row scores, meaningful for tid < BN
            for (int m = 0; m < NMOD; ++m) {
                float p[2][4];
                if (bias) {
                    float v4[4];
                    #pragma unroll
                    for (int j = 0; j < 4; ++j)
                        v4[j] = out[VOFF + m * DDIM + w * 64 + j * 16 + c];
                    #pragma unroll
                    for (int rt = 0; rt < 2; ++rt)
                        #pragma unroll
                        for (int reg = 0; reg < 4; ++reg) {
                            int r = rt * 16 + g * 4 + reg;
                            float tacc = 0.f;
                            #pragma unroll
                            for (int j = 0; j < 4; ++j) {
                                int col = w * 64 + j * 16 + c;
                                float xv = (float)*(const __bf16*)((const char*)tile +
                                                                   SWZ(r, col * 2));
                                tacc += xv * v4[j];
                            }
                            p[rt][reg] = tacc;
                        }
                } else {
                    #pragma unroll
                    for (int rt = 0; rt < 2; ++rt)
                        #pragma unroll
                        for (int reg = 0; reg < 4; ++reg)
                            p[rt][reg] = 0.f;
                }

                const __bf16* gm = Gp + (size_t)m * 262144;   // 512KB per m
                #pragma unroll
                for (int jh = 0; jh < 2; ++jh) {
                    f32x4 kacc[2][2];
                    #pragma unroll
                    for (int rt = 0; rt < 2; ++rt) {
                        kacc[rt][0] = (f32x4){0.f, 0.f, 0.f, 0.f};
                        kacc[rt][1] = (f32x4){0.f, 0.f, 0.f, 0.f};
                    }
                    // packed b-loads: one contiguous 1KB read per fragment
                    const __bf16* gpk = gm + (w * 4 + jh * 2) * 512 + lane * 8;
                    #pragma unroll 4
                    for (int kk = 0; kk < 16; ++kk) {
                        bf16x8 b0 = *(const bf16x8*)(gpk + kk * 16384);
                        bf16x8 b1 = *(const bf16x8*)(gpk + kk * 16384 + 512);
                        bf16x8 a[2];
                        const int kb = kk * 64 + g * 16;
                        a[0] = *(const bf16x8*)((const char*)tile + SWZ(c, kb));
                        a[1] = *(const bf16x8*)((const char*)tile + SWZ(16 + c, kb));
                        kacc[0][0] = __builtin_amdgcn_mfma_f32_16x16x32_bf16(
                            a[0], b0, kacc[0][0], 0, 0, 0);
                        kacc[1][0] = __builtin_amdgcn_mfma_f32_16x16x32_bf16(
                            a[1], b0, kacc[1][0], 0, 0, 0);
                        kacc[0][1] = __builtin_amdgcn_mfma_f32_16x16x32_bf16(
                            a[0], b1, kacc[0][1], 0, 0, 0);
                        kacc[1][1] = __builtin_amdgcn_mfma_f32_16x16x32_bf16(
                            a[1], b1, kacc[1][1], 0, 0, 0);
                    }
                    // dot with l, 8 lv regs at a time (stay under 64-reg cap)
                    #pragma unroll
                    for (int jj = 0; jj < 2; ++jj) {
                        const int e = w * 64 + (jh * 2 + jj) * 16 + c;
                        float uj = bias ? out[UOFF + m * DDIM + e] : 0.f;
                        float lv[2][4];
                        #pragma unroll
                        for (int rt = 0; rt < 2; ++rt)
                            #pragma unroll
                            for (int reg = 0; reg < 4; ++reg) {
                                int row = row0 + rt * 16 + g * 4 + reg;
                                lv[rt][reg] = (row < NTOK)
                                    ? __builtin_nontemporal_load(
                                          lat + ((size_t)row * NMOD + m) * DDIM + e)
                                    : 0.f;
                            }
                        #pragma unroll
                        for (int rt = 0; rt < 2; ++rt)
                            #pragma unroll
                            for (int reg = 0; reg < 4; ++reg)
                                p[rt][reg] += lv[rt][reg] * (kacc[rt][jj][reg] + uj);
                    }
                    __builtin_amdgcn_sched_barrier(0);
                }

                // reduce over 16 c-lanes, then across 8 waves via LDS (dbuf)
                #pragma unroll
                for (int msk = 1; msk < 16; msk <<= 1)
                    #pragma unroll
                    for (int rt = 0; rt < 2; ++rt)
                        #pragma unroll
                        for (int reg = 0; reg < 4; ++reg)
                            p[rt][reg] += __shfl_xor(p[rt][reg], msk, 64);
                float* sp = s_part + (m & 1) * 256;
                if (c == 0) {
                    #pragma unroll
                    for (int rt = 0; rt < 2; ++rt)
                        #pragma unroll
                        for (int reg = 0; reg < 4; ++reg)
                            sp[w * 32 + rt * 16 + g * 4 + reg] = p[rt][reg];
                }
                __syncthreads();                 // s_part[m&1] complete
                if (tid < BN) {
                    float s = 0.f;
                    #pragma unroll
                    for (int ww = 0; ww < 8; ++ww) s += sp[ww * 32 + tid];
                    sm[m] = s + cm[m];
                }
                // no second barrier: next m writes the OTHER s_part buffer
            }

            if (tid < BN && row0 + tid < NTOK) {
                float e0 = __expf(sm[0] * SCALE), e1 = __expf(sm[1] * SCALE),
                      e2 = __expf(sm[2] * SCALE), e3 = __expf(sm[3] * SCALE);
                float iz = 1.f / (e0 + e1 + e2 + e3);
                f32x4 wv = {e0 * iz, e1 * iz, e2 * iz, e3 * iz};
                *(f32x4*)(out + WOFF + (size_t)(row0 + tid) * 4) = wv;
            }
            __syncthreads();   // tile/s_part reads done before next tile
        }
    }
    gg.sync();   // weights visible; G/u/v/c/flags region now dead

    // ===== phase 3: fused = sum_m w_m L_m (flat coalesced walk) =====
    {
        const long total4 = (long)NTOK * (DDIM / 4);          // 6,400,000
        for (long idx = (long)bid * 512 + tid; idx < total4;
             idx += (long)ngrid * 512) {
            const int row = (int)(idx >> 7), c4 = (int)(idx & 127);
            f32x4 w4 = *(const f32x4*)(out + WOFF + (size_t)row * 4);
            f32x4 acc = {0.f, 0.f, 0.f, 0.f};
            #pragma unroll
            for (int m = 0; m < NMOD; ++m) {
                f32x4 v = __builtin_nontemporal_load(
                    (const f32x4*)(lat + ((size_t)row * NMOD + m) * DDIM + c4 * 4));
                acc += w4[m] * v;
            }
            __builtin_nontemporal_store(acc, (f32x4*)(out + (size_t)idx * 4));
        }
    }
}

extern "C" void kernel_launch(void* const* d_in, const int* in_sizes, int n_in,
                              void* d_out, int out_size, void* d_ws, size_t ws_size,
                              hipStream_t stream)
{
    const float* gnn = (const float*)d_in[0];   // [N, D]
    const float* lat = (const float*)d_in[1];   // [N, M, D]
    const float* Wq  = (const float*)d_in[2];   // [D, D]
    const float* bq  = (const float*)d_in[3];   // [D]
    const float* Wk  = (const float*)d_in[4];   // [M, D, D]
    const float* bk  = (const float*)d_in[5];   // [M, D]
    float* out = (float*)d_out;                 // fused [N,D] ++ weights [N,M]

    int maxb = 0;
    hipError_t oe = hipOccupancyMaxActiveBlocksPerMultiprocessor(
        &maxb, mono_kernel, 512, 0);
    if (oe != hipSuccess || maxb < 1) maxb = 1;
    if (maxb > 4) maxb = 4;
    const int ngrid = 256 * maxb;

    void* args[] = { (void*)&gnn, (void*)&lat, (void*)&Wq, (void*)&bq,
                     (void*)&Wk, (void*)&bk, (void*)&out };
    hipLaunchCooperativeKernel((const void*)mono_kernel, dim3(ngrid), dim3(512),
                               args, 0, stream);
}

// Round 14
// 689.452 us; speedup vs baseline: 1.2667x; 1.0114x over previous
//
#include <hip/hip_runtime.h>
#include <hip/hip_cooperative_groups.h>

namespace cg = cooperative_groups;

// ---------------------------------------------------------------------------
// InterpretableFusion v14 — ONE cooperative kernel, grid.sync-fenced phases.
//   scores[n,m] = ( x.(G_m l) + x.v_m + l.u_m + c_m )/sqrt(D)
//   y = x Gt_m^T via MFMA (packed-G b-fragments, X tile staged once),
//   s = (y+u).l with l loaded from global.
// v13 -> v14: INLINE FUSE. G/u/v/c scratch moves to the TAIL of the fused
// region (out[25.0M..25.53M), rows >= 48828). Tiles t < 1525 fuse their own
// 32 rows immediately after softmax: lat rows are L2/L3-hot from the lv
// reads (L3=256MB -> guaranteed hit), weights in LDS, and fused rows <48800
// never overlap scratch -> no v5-style race. Kills phase 3's 512MB cold HBM
// re-stream (~200us). 38 tail tiles defer to a tiny post-sync phase.
// Spill-trim at the 64-VGPR cap: k-loop unroll 2, staged loads 4-at-a-time.
// ---------------------------------------------------------------------------

typedef __bf16 bf16x8 __attribute__((ext_vector_type(8)));
typedef __bf16 bf16x4 __attribute__((ext_vector_type(4)));
typedef float  f32x4  __attribute__((ext_vector_type(4)));

#define NTOK 50000
#define DDIM 512
#define NMOD 4
#define BN   32
#define NBLK ((NTOK + BN - 1) / BN)        // 1563
#define WOFF ((size_t)NTOK * DDIM)         // weights region (float offset)
#define SB   25000000                      // scratch base = tail of fused rows
#define UOFF (SB + 524288)                 // u[m][d']
#define VOFF (UOFF + 2048)                 // v[m][d]
#define COFF (VOFF + 2048)                 // c[m]
#define FOFF (COFF + 4)                    // 32 bias-nonzero flags
#define TAIL_T 1525                        // tiles >= this defer the fuse
#define SCALE 0.044194173824159216f        // 1/sqrt(512)

// X-tile swizzle: row stride 1024B; XOR byte bits 4-6 with row&7 (guide §6 G4)
#define SWZ(r, b) ((((r) * 1024) + (b)) ^ (((r) & 7) << 4))

__global__ __launch_bounds__(512, 4) void mono_kernel(
    const float* __restrict__ gnn, const float* __restrict__ lat,
    const float* __restrict__ Wq, const float* __restrict__ bq,
    const float* __restrict__ Wk, const float* __restrict__ bk,
    float* __restrict__ out)
{
    __shared__ __align__(16) char smem[35328];  // 32K tile + s_part dbuf + wlds
    const int tid = threadIdx.x;
    const int bid = blockIdx.x;
    const int ngrid = gridDim.x;
    cg::grid_group gg = cg::this_grid();

    // ===== phase 1: Gt[m][e][d] = sum_r Wk[m][r][e]*Wq[r][d], PACKED store ===
    {
        float* ldsA = (float*)smem;            // [r][64 e-cols of Wk_m]
        float* ldsB = (float*)(smem + 16384);  // [r][32 d-cols of Wq]
        for (int gb = bid; gb < 512; gb += ngrid) {
            const int m = gb >> 7, ib = gb & 127, eblk = ib >> 4, dpb = ib & 15;
            const int el = tid >> 3, c8 = tid & 7;
            f32x4 ac = {0.f, 0.f, 0.f, 0.f};
            for (int r0 = 0; r0 < DDIM; r0 += 64) {
                __syncthreads();
                #pragma unroll
                for (int it = 0; it < 2; ++it) {
                    int idx = it * 512 + tid, r = idx >> 4, c4 = idx & 15;
                    *(f32x4*)&ldsA[r * 64 + c4 * 4] =
                        *(const f32x4*)&Wk[((size_t)m * DDIM + r0 + r) * DDIM + eblk * 64 + c4 * 4];
                }
                {
                    int r = tid >> 3, c4 = tid & 7;
                    *(f32x4*)&ldsB[r * 32 + c4 * 4] =
                        *(const f32x4*)&Wq[(size_t)(r0 + r) * DDIM + dpb * 32 + c4 * 4];
                }
                __syncthreads();
                for (int r = 0; r < 64; ++r) {
                    float wk = ldsA[r * 64 + el];
                    ac += wk * *(const f32x4*)&ldsB[r * 32 + c8 * 4];
                }
            }
            // packed store: element (e,d): kk=d>>5, g=(d>>3)&3, eta=e>>4,
            // lane = g*16+(e&15); 16B-unit = ((m*16+kk)*32+eta)*64+lane
            __bf16* Gw = (__bf16*)(out + SB);
            const int eta = eblk * 4 + (el >> 4);
            const int lam = (c8 >> 1) * 16 + (el & 15);
            size_t abf = ((((size_t)m * 16 + dpb) * 32 + eta) * 64 + lam) * 8
                         + (c8 & 1) * 4;
            bf16x4 o;
            o[0] = (__bf16)ac[0]; o[1] = (__bf16)ac[1];
            o[2] = (__bf16)ac[2]; o[3] = (__bf16)ac[3];
            *(bf16x4*)(Gw + abf) = o;
        }

        if (bid < 32) {                        // u, v, c + bias flags
            __syncthreads();                   // own block's LDS reads done
            float* up = (float*)smem;          // [4][64]
            float* vp = (float*)smem + 256;    // [4][64]
            const int m2 = bid >> 3, dc = bid & 7;
            if (tid < 256) {
                const int dl2 = tid & 63, eg = tid >> 6;
                const int d = dc * 64 + dl2;
                float us = 0.f, vs = 0.f;
                #pragma unroll 4
                for (int e = eg * 128; e < eg * 128 + 128; ++e) {
                    us += Wk[((size_t)m2 * DDIM + e) * DDIM + d] * bq[e];
                    vs += Wq[(size_t)e * DDIM + d] * bk[m2 * DDIM + e];
                }
                up[eg * 64 + dl2] = us; vp[eg * 64 + dl2] = vs;
            }
            __syncthreads();
            if (tid < 64) {
                const int d = dc * 64 + tid;
                float uu = up[tid] + up[64+tid] + up[128+tid] + up[192+tid];
                float vv = vp[tid] + vp[64+tid] + vp[128+tid] + vp[192+tid];
                out[UOFF + m2 * DDIM + d] = uu;
                out[VOFF + m2 * DDIM + d] = vv;
                float cp = 0.f;
                if (dc == 0) {
                    #pragma unroll
                    for (int i = 0; i < 8; ++i)
                        cp += bq[tid * 8 + i] * bk[m2 * DDIM + tid * 8 + i];
                    #pragma unroll
                    for (int msk = 1; msk < 64; msk <<= 1)
                        cp += __shfl_xor(cp, msk, 64);
                    if (tid == 0) out[COFF + m2] = cp;
                }
                unsigned long long anyb =
                    __ballot((uu != 0.f) || (vv != 0.f) || (cp != 0.f));
                if (tid == 0) out[FOFF + bid] = anyb ? 1.f : 0.f;  // always written
            }
        }
    }
    gg.sync();   // packed Gt/u/v/c/flags visible device-wide

    // ===== phase 2: scores -> softmax -> weights -> INLINE fuse =====
    {
        __bf16* tile  = (__bf16*)smem;             // 32 KiB: X tile
        float* s_part = (float*)(smem + 32768);    // 2 x [8][32] double buffer
        f32x4* wlds   = (f32x4*)(smem + 34816);    // [32] normalized weights
        const __bf16* Gp = (const __bf16*)(out + SB);
        const int lane = tid & 63, w = tid >> 6;
        const int g = (lane >> 4) & 3, c = lane & 15;

        bool bias = false;
        for (int i2 = 0; i2 < 32; ++i2) bias |= (out[FOFF + i2] != 0.f);
        float cm[4];
        #pragma unroll
        for (int m = 0; m < 4; ++m) cm[m] = out[COFF + m];

        for (int t = bid; t < NBLK; t += ngrid) {
            const int row0 = t * BN;
            const int vrows = (NTOK - row0 < BN) ? (NTOK - row0) : BN;

            {   // stage X once per tile (two 4-deep chunks to cap reg peak)
                const float* src = gnn + (size_t)row0 * DDIM;
                #pragma unroll
                for (int half = 0; half < 2; ++half) {
                    #pragma unroll
                    for (int i = 0; i < 4; ++i) {
                        int f4 = (half * 4 + i) * 512 + tid, r = f4 >> 7, c4 = f4 & 127;
                        f32x4 v = (r < vrows)
                            ? __builtin_nontemporal_load(
                                  (const f32x4*)(src + (size_t)r * DDIM + c4 * 4))
                            : (f32x4){0.f, 0.f, 0.f, 0.f};
                        bf16x4 o;
                        o[0] = (__bf16)v[0]; o[1] = (__bf16)v[1];
                        o[2] = (__bf16)v[2]; o[3] = (__bf16)v[3];
                        *(bf16x4*)((char*)tile + SWZ(r, c4 * 8)) = o;
                    }
                    __builtin_amdgcn_sched_barrier(0);
                }
            }
            __syncthreads();

            float sm[4];   // per-row scores, meaningful for tid < BN
            for (int m = 0; m < NMOD; ++m) {
                float p[2][4];
                if (bias) {
                    float v4[4];
                    #pragma unroll
                    for (int j = 0; j < 4; ++j)
                        v4[j] = out[VOFF + m * DDIM + w * 64 + j * 16 + c];
                    #pragma unroll
                    for (int rt = 0; rt < 2; ++rt)
                        #pragma unroll
                        for (int reg = 0; reg < 4; ++reg) {
                            int r = rt * 16 + g * 4 + reg;
                            float tacc = 0.f;
                            #pragma unroll
                            for (int j = 0; j < 4; ++j) {
                                int col = w * 64 + j * 16 + c;
                                float xv = (float)*(const __bf16*)((const char*)tile +
                                                                   SWZ(r, col * 2));
                                tacc += xv * v4[j];
                            }
                            p[rt][reg] = tacc;
                        }
                } else {
                    #pragma unroll
                    for (int rt = 0; rt < 2; ++rt)
                        #pragma unroll
                        for (int reg = 0; reg < 4; ++reg)
                            p[rt][reg] = 0.f;
                }

                const __bf16* gm = Gp + (size_t)m * 262144;   // 512KB per m
                #pragma unroll
                for (int jh = 0; jh < 2; ++jh) {
                    f32x4 kacc[2][2];
                    #pragma unroll
                    for (int rt = 0; rt < 2; ++rt) {
                        kacc[rt][0] = (f32x4){0.f, 0.f, 0.f, 0.f};
                        kacc[rt][1] = (f32x4){0.f, 0.f, 0.f, 0.f};
                    }
                    // packed b-loads: one contiguous 1KB wave read per fragment
                    const __bf16* gpk = gm + (w * 4 + jh * 2) * 512 + lane * 8;
                    #pragma unroll 2
                    for (int kk = 0; kk < 16; ++kk) {
                        bf16x8 b0 = *(const bf16x8*)(gpk + kk * 16384);
                        bf16x8 b1 = *(const bf16x8*)(gpk + kk * 16384 + 512);
                        bf16x8 a[2];
                        const int kb = kk * 64 + g * 16;
                        a[0] = *(const bf16x8*)((const char*)tile + SWZ(c, kb));
                        a[1] = *(const bf16x8*)((const char*)tile + SWZ(16 + c, kb));
                        kacc[0][0] = __builtin_amdgcn_mfma_f32_16x16x32_bf16(
                            a[0], b0, kacc[0][0], 0, 0, 0);
                        kacc[1][0] = __builtin_amdgcn_mfma_f32_16x16x32_bf16(
                            a[1], b0, kacc[1][0], 0, 0, 0);
                        kacc[0][1] = __builtin_amdgcn_mfma_f32_16x16x32_bf16(
                            a[0], b1, kacc[0][1], 0, 0, 0);
                        kacc[1][1] = __builtin_amdgcn_mfma_f32_16x16x32_bf16(
                            a[1], b1, kacc[1][1], 0, 0, 0);
                    }
                    // dot with l (regular loads: lines stay cached for the
                    // inline fuse below), 8 lv regs at a time
                    #pragma unroll
                    for (int jj = 0; jj < 2; ++jj) {
                        const int e = w * 64 + (jh * 2 + jj) * 16 + c;
                        float uj = bias ? out[UOFF + m * DDIM + e] : 0.f;
                        float lv[2][4];
                        #pragma unroll
                        for (int rt = 0; rt < 2; ++rt)
                            #pragma unroll
                            for (int reg = 0; reg < 4; ++reg) {
                                int row = row0 + rt * 16 + g * 4 + reg;
                                lv[rt][reg] = (row < NTOK)
                                    ? lat[((size_t)row * NMOD + m) * DDIM + e]
                                    : 0.f;
                            }
                        #pragma unroll
                        for (int rt = 0; rt < 2; ++rt)
                            #pragma unroll
                            for (int reg = 0; reg < 4; ++reg)
                                p[rt][reg] += lv[rt][reg] * (kacc[rt][jj][reg] + uj);
                    }
                    __builtin_amdgcn_sched_barrier(0);
                }

                // reduce over 16 c-lanes, then across 8 waves via LDS (dbuf)
                #pragma unroll
                for (int msk = 1; msk < 16; msk <<= 1)
                    #pragma unroll
                    for (int rt = 0; rt < 2; ++rt)
                        #pragma unroll
                        for (int reg = 0; reg < 4; ++reg)
                            p[rt][reg] += __shfl_xor(p[rt][reg], msk, 64);
                float* sp = s_part + (m & 1) * 256;
                if (c == 0) {
                    #pragma unroll
                    for (int rt = 0; rt < 2; ++rt)
                        #pragma unroll
                        for (int reg = 0; reg < 4; ++reg)
                            sp[w * 32 + rt * 16 + g * 4 + reg] = p[rt][reg];
                }
                __syncthreads();                 // s_part[m&1] complete
                if (tid < BN) {
                    float s = 0.f;
                    #pragma unroll
                    for (int ww = 0; ww < 8; ++ww) s += sp[ww * 32 + tid];
                    sm[m] = s + cm[m];
                }
                // no second barrier: next m writes the OTHER s_part buffer
            }

            if (tid < BN) {
                float e0 = __expf(sm[0] * SCALE), e1 = __expf(sm[1] * SCALE),
                      e2 = __expf(sm[2] * SCALE), e3 = __expf(sm[3] * SCALE);
                float iz = 1.f / (e0 + e1 + e2 + e3);
                f32x4 wv = {e0 * iz, e1 * iz, e2 * iz, e3 * iz};
                wlds[tid] = wv;
                if (row0 + tid < NTOK)
                    *(f32x4*)(out + WOFF + (size_t)(row0 + tid) * 4) = wv;
            }
            __syncthreads();                     // wlds ready

            // ---- inline fuse: this tile's lat rows are L2/L3-hot from lv ----
            if (t < TAIL_T) {                    // fused rows < 48800 < SB rows
                #pragma unroll 2
                for (int i = 0; i < 8; ++i) {
                    int f4 = i * 512 + tid, r = f4 >> 7, c4 = f4 & 127;
                    f32x4 w4 = wlds[r];
                    const float* lp = lat + (size_t)(row0 + r) * NMOD * DDIM + c4 * 4;
                    f32x4 acc = {0.f, 0.f, 0.f, 0.f};
                    #pragma unroll
                    for (int m = 0; m < NMOD; ++m)
                        acc += w4[m] * *(const f32x4*)(lp + m * DDIM);
                    __builtin_nontemporal_store(acc,
                        (f32x4*)(out + (size_t)(row0 + r) * DDIM + c4 * 4));
                }
            }
            // no trailing barrier needed: next tile's stage touches only
            // `tile`, whose last reads completed before the m=3 barrier;
            // wlds is next written 5 barriers from now.
        }
    }
    gg.sync();   // all weights visible; scratch region now dead

    // ===== phase 3: fuse ONLY the 38 tail tiles (rows 48800..49999) =====
    {
        const long t4 = (long)(NTOK - TAIL_T * BN) * 128;   // 153,600
        for (long idx = (long)bid * 512 + tid; idx < t4;
             idx += (long)ngrid * 512) {
            const int row = TAIL_T * BN + (int)(idx >> 7), c4 = (int)(idx & 127);
            f32x4 w4 = *(const f32x4*)(out + WOFF + (size_t)row * 4);
            f32x4 acc = {0.f, 0.f, 0.f, 0.f};
            #pragma unroll
            for (int m = 0; m < NMOD; ++m) {
                f32x4 v = __builtin_nontemporal_load(
                    (const f32x4*)(lat + ((size_t)row * NMOD + m) * DDIM + c4 * 4));
                acc += w4[m] * v;
            }
            __builtin_nontemporal_store(acc,
                (f32x4*)(out + (size_t)row * DDIM + c4 * 4));
        }
    }
}

extern "C" void kernel_launch(void* const* d_in, const int* in_sizes, int n_in,
                              void* d_out, int out_size, void* d_ws, size_t ws_size,
                              hipStream_t stream)
{
    const float* gnn = (const float*)d_in[0];   // [N, D]
    const float* lat = (const float*)d_in[1];   // [N, M, D]
    const float* Wq  = (const float*)d_in[2];   // [D, D]
    const float* bq  = (const float*)d_in[3];   // [D]
    const float* Wk  = (const float*)d_in[4];   // [M, D, D]
    const float* bk  = (const float*)d_in[5];   // [M, D]
    float* out = (float*)d_out;                 // fused [N,D] ++ weights [N,M]

    int maxb = 0;
    hipError_t oe = hipOccupancyMaxActiveBlocksPerMultiprocessor(
        &maxb, mono_kernel, 512, 0);
    if (oe != hipSuccess || maxb < 1) maxb = 1;
    if (maxb > 4) maxb = 4;
    const int ngrid = 256 * maxb;

    void* args[] = { (void*)&gnn, (void*)&lat, (void*)&Wq, (void*)&bq,
                     (void*)&Wk, (void*)&bk, (void*)&out };
    hipLaunchCooperativeKernel((const void*)mono_kernel, dim3(ngrid), dim3(512),
                               args, 0, stream);
}

// Round 15
// 610.153 us; speedup vs baseline: 1.4313x; 1.1300x over previous
//
#include <hip/hip_runtime.h>
#include <hip/hip_cooperative_groups.h>

namespace cg = cooperative_groups;

// ---------------------------------------------------------------------------
// InterpretableFusion v15 — ONE cooperative kernel, ONE grid.sync (d_ws path).
//   scores[n,m] = ( x.(G_m l) + x.v_m + l.u_m + c_m )/sqrt(D)
//   y = x Gt_m^T via MFMA (packed-G b-fragments, X tile staged once),
//   s = (y+u).l, softmax -> weights; fused inline per tile (lat L2-hot).
// v14 -> v15: scratch (packed G, u, v, c, flags) moves to d_ws. Within a
// single cooperative kernel, d_ws + grid.sync is the documented-correct
// visibility mechanism (round-1's d_ws failure was MULTI-KERNEL cross-node
// coherence). With scratch out of the fused region, ALL tiles fuse inline
// -> phase 3 and the SECOND grid.sync disappear. Hypothesis under test:
// grid.sync on 8 XCDs costs ~100-200us each (explains why occupancy and
// spill knobs barely moved the 600us plateau).
// Fallback (ws_size < 3MB): v14's out-tail scratch + deferred tail tiles +
// second sync, selected by a grid-uniform kernel arg.
// ---------------------------------------------------------------------------

typedef __bf16 bf16x8 __attribute__((ext_vector_type(8)));
typedef __bf16 bf16x4 __attribute__((ext_vector_type(4)));
typedef float  f32x4  __attribute__((ext_vector_type(4)));

#define NTOK 50000
#define DDIM 512
#define NMOD 4
#define BN   32
#define NBLK ((NTOK + BN - 1) / BN)        // 1563
#define WOFF ((size_t)NTOK * DDIM)         // weights region (float offset)
#define GFLOATS 524288                     // packed G: 2MB = 524288 floats
#define TAIL_T 1525                        // fallback: tiles >= this defer fuse
#define SCALE 0.044194173824159216f        // 1/sqrt(512)

// X-tile swizzle: row stride 1024B; XOR byte bits 4-6 with row&7 (guide §6 G4)
#define SWZ(r, b) ((((r) * 1024) + (b)) ^ (((r) & 7) << 4))

__global__ __launch_bounds__(512, 4) void mono_kernel(
    const float* __restrict__ gnn, const float* __restrict__ lat,
    const float* __restrict__ Wq, const float* __restrict__ bq,
    const float* __restrict__ Wk, const float* __restrict__ bk,
    float* __restrict__ out, float* __restrict__ sc, int defer)
{
    __shared__ __align__(16) char smem[35328];  // 32K tile + s_part dbuf + wlds
    const int tid = threadIdx.x;
    const int bid = blockIdx.x;
    const int ngrid = gridDim.x;
    cg::grid_group gg = cg::this_grid();

    float* uP = sc + GFLOATS;          // u[m][d']  (4*512)
    float* vP = uP + 2048;             // v[m][d]
    float* cP = vP + 2048;             // c[m]
    float* fP = cP + 4;                // 32 bias-nonzero flags

    // ===== phase 1: Gt[m][e][d] = sum_r Wk[m][r][e]*Wq[r][d], PACKED store ===
    {
        float* ldsA = (float*)smem;            // [r][64 e-cols of Wk_m]
        float* ldsB = (float*)(smem + 16384);  // [r][32 d-cols of Wq]
        for (int gb = bid; gb < 512; gb += ngrid) {
            const int m = gb >> 7, ib = gb & 127, eblk = ib >> 4, dpb = ib & 15;
            const int el = tid >> 3, c8 = tid & 7;
            f32x4 ac = {0.f, 0.f, 0.f, 0.f};
            for (int r0 = 0; r0 < DDIM; r0 += 64) {
                __syncthreads();
                #pragma unroll
                for (int it = 0; it < 2; ++it) {
                    int idx = it * 512 + tid, r = idx >> 4, c4 = idx & 15;
                    *(f32x4*)&ldsA[r * 64 + c4 * 4] =
                        *(const f32x4*)&Wk[((size_t)m * DDIM + r0 + r) * DDIM + eblk * 64 + c4 * 4];
                }
                {
                    int r = tid >> 3, c4 = tid & 7;
                    *(f32x4*)&ldsB[r * 32 + c4 * 4] =
                        *(const f32x4*)&Wq[(size_t)(r0 + r) * DDIM + dpb * 32 + c4 * 4];
                }
                __syncthreads();
                for (int r = 0; r < 64; ++r) {
                    float wk = ldsA[r * 64 + el];
                    ac += wk * *(const f32x4*)&ldsB[r * 32 + c8 * 4];
                }
            }
            // packed store: element (e,d): kk=d>>5, g=(d>>3)&3, eta=e>>4,
            // lane = g*16+(e&15); 16B-unit = ((m*16+kk)*32+eta)*64+lane
            __bf16* Gw = (__bf16*)sc;
            const int eta = eblk * 4 + (el >> 4);
            const int lam = (c8 >> 1) * 16 + (el & 15);
            size_t abf = ((((size_t)m * 16 + dpb) * 32 + eta) * 64 + lam) * 8
                         + (c8 & 1) * 4;
            bf16x4 o;
            o[0] = (__bf16)ac[0]; o[1] = (__bf16)ac[1];
            o[2] = (__bf16)ac[2]; o[3] = (__bf16)ac[3];
            *(bf16x4*)(Gw + abf) = o;
        }

        if (bid < 32) {                        // u, v, c + bias flags
            __syncthreads();                   // own block's LDS reads done
            float* up = (float*)smem;          // [4][64]
            float* vp = (float*)smem + 256;    // [4][64]
            const int m2 = bid >> 3, dc = bid & 7;
            if (tid < 256) {
                const int dl2 = tid & 63, eg = tid >> 6;
                const int d = dc * 64 + dl2;
                float us = 0.f, vs = 0.f;
                #pragma unroll 4
                for (int e = eg * 128; e < eg * 128 + 128; ++e) {
                    us += Wk[((size_t)m2 * DDIM + e) * DDIM + d] * bq[e];
                    vs += Wq[(size_t)e * DDIM + d] * bk[m2 * DDIM + e];
                }
                up[eg * 64 + dl2] = us; vp[eg * 64 + dl2] = vs;
            }
            __syncthreads();
            if (tid < 64) {
                const int d = dc * 64 + tid;
                float uu = up[tid] + up[64+tid] + up[128+tid] + up[192+tid];
                float vv = vp[tid] + vp[64+tid] + vp[128+tid] + vp[192+tid];
                uP[m2 * DDIM + d] = uu;
                vP[m2 * DDIM + d] = vv;
                float cp = 0.f;
                if (dc == 0) {
                    #pragma unroll
                    for (int i = 0; i < 8; ++i)
                        cp += bq[tid * 8 + i] * bk[m2 * DDIM + tid * 8 + i];
                    #pragma unroll
                    for (int msk = 1; msk < 64; msk <<= 1)
                        cp += __shfl_xor(cp, msk, 64);
                    if (tid == 0) cP[m2] = cp;
                }
                unsigned long long anyb =
                    __ballot((uu != 0.f) || (vv != 0.f) || (cp != 0.f));
                if (tid == 0) fP[bid] = anyb ? 1.f : 0.f;   // always written
            }
        }
    }
    gg.sync();   // packed Gt/u/v/c/flags visible device-wide (THE one sync)

    // ===== phase 2: scores -> softmax -> weights -> INLINE fuse =====
    {
        __bf16* tile  = (__bf16*)smem;             // 32 KiB: X tile
        float* s_part = (float*)(smem + 32768);    // 2 x [8][32] double buffer
        f32x4* wlds   = (f32x4*)(smem + 34816);    // [32] normalized weights
        const __bf16* Gp = (const __bf16*)sc;
        const int lane = tid & 63, w = tid >> 6;
        const int g = (lane >> 4) & 3, c = lane & 15;

        bool bias = false;
        for (int i2 = 0; i2 < 32; ++i2) bias |= (fP[i2] != 0.f);
        float cm[4];
        #pragma unroll
        for (int m = 0; m < 4; ++m) cm[m] = cP[m];

        for (int t = bid; t < NBLK; t += ngrid) {
            const int row0 = t * BN;
            const int vrows = (NTOK - row0 < BN) ? (NTOK - row0) : BN;

            {   // stage X once per tile (two 4-deep chunks to cap reg peak)
                const float* src = gnn + (size_t)row0 * DDIM;
                #pragma unroll
                for (int half = 0; half < 2; ++half) {
                    #pragma unroll
                    for (int i = 0; i < 4; ++i) {
                        int f4 = (half * 4 + i) * 512 + tid, r = f4 >> 7, c4 = f4 & 127;
                        f32x4 v = (r < vrows)
                            ? __builtin_nontemporal_load(
                                  (const f32x4*)(src + (size_t)r * DDIM + c4 * 4))
                            : (f32x4){0.f, 0.f, 0.f, 0.f};
                        bf16x4 o;
                        o[0] = (__bf16)v[0]; o[1] = (__bf16)v[1];
                        o[2] = (__bf16)v[2]; o[3] = (__bf16)v[3];
                        *(bf16x4*)((char*)tile + SWZ(r, c4 * 8)) = o;
                    }
                    __builtin_amdgcn_sched_barrier(0);
                }
            }
            __syncthreads();

            float sm[4];   // per-row scores, meaningful for tid < BN
            for (int m = 0; m < NMOD; ++m) {
                float p[2][4];
                if (bias) {
                    float v4[4];
                    #pragma unroll
                    for (int j = 0; j < 4; ++j)
                        v4[j] = vP[m * DDIM + w * 64 + j * 16 + c];
                    #pragma unroll
                    for (int rt = 0; rt < 2; ++rt)
                        #pragma unroll
                        for (int reg = 0; reg < 4; ++reg) {
                            int r = rt * 16 + g * 4 + reg;
                            float tacc = 0.f;
                            #pragma unroll
                            for (int j = 0; j < 4; ++j) {
                                int col = w * 64 + j * 16 + c;
                                float xv = (float)*(const __bf16*)((const char*)tile +
                                                                   SWZ(r, col * 2));
                                tacc += xv * v4[j];
                            }
                            p[rt][reg] = tacc;
                        }
                } else {
                    #pragma unroll
                    for (int rt = 0; rt < 2; ++rt)
                        #pragma unroll
                        for (int reg = 0; reg < 4; ++reg)
                            p[rt][reg] = 0.f;
                }

                const __bf16* gm = Gp + (size_t)m * 262144;   // 512KB per m
                #pragma unroll
                for (int jh = 0; jh < 2; ++jh) {
                    f32x4 kacc[2][2];
                    #pragma unroll
                    for (int rt = 0; rt < 2; ++rt) {
                        kacc[rt][0] = (f32x4){0.f, 0.f, 0.f, 0.f};
                        kacc[rt][1] = (f32x4){0.f, 0.f, 0.f, 0.f};
                    }
                    // packed b-loads: one contiguous 1KB wave read per fragment
                    const __bf16* gpk = gm + (w * 4 + jh * 2) * 512 + lane * 8;
                    #pragma unroll 2
                    for (int kk = 0; kk < 16; ++kk) {
                        bf16x8 b0 = *(const bf16x8*)(gpk + kk * 16384);
                        bf16x8 b1 = *(const bf16x8*)(gpk + kk * 16384 + 512);
                        bf16x8 a[2];
                        const int kb = kk * 64 + g * 16;
                        a[0] = *(const bf16x8*)((const char*)tile + SWZ(c, kb));
                        a[1] = *(const bf16x8*)((const char*)tile + SWZ(16 + c, kb));
                        kacc[0][0] = __builtin_amdgcn_mfma_f32_16x16x32_bf16(
                            a[0], b0, kacc[0][0], 0, 0, 0);
                        kacc[1][0] = __builtin_amdgcn_mfma_f32_16x16x32_bf16(
                            a[1], b0, kacc[1][0], 0, 0, 0);
                        kacc[0][1] = __builtin_amdgcn_mfma_f32_16x16x32_bf16(
                            a[0], b1, kacc[0][1], 0, 0, 0);
                        kacc[1][1] = __builtin_amdgcn_mfma_f32_16x16x32_bf16(
                            a[1], b1, kacc[1][1], 0, 0, 0);
                    }
                    // dot with l (regular loads: lines stay cached for the
                    // inline fuse below), 8 lv regs at a time
                    #pragma unroll
                    for (int jj = 0; jj < 2; ++jj) {
                        const int e = w * 64 + (jh * 2 + jj) * 16 + c;
                        float uj = bias ? uP[m * DDIM + e] : 0.f;
                        float lv[2][4];
                        #pragma unroll
                        for (int rt = 0; rt < 2; ++rt)
                            #pragma unroll
                            for (int reg = 0; reg < 4; ++reg) {
                                int row = row0 + rt * 16 + g * 4 + reg;
                                lv[rt][reg] = (row < NTOK)
                                    ? lat[((size_t)row * NMOD + m) * DDIM + e]
                                    : 0.f;
                            }
                        #pragma unroll
                        for (int rt = 0; rt < 2; ++rt)
                            #pragma unroll
                            for (int reg = 0; reg < 4; ++reg)
                                p[rt][reg] += lv[rt][reg] * (kacc[rt][jj][reg] + uj);
                    }
                    __builtin_amdgcn_sched_barrier(0);
                }

                // reduce over 16 c-lanes, then across 8 waves via LDS (dbuf)
                #pragma unroll
                for (int msk = 1; msk < 16; msk <<= 1)
                    #pragma unroll
                    for (int rt = 0; rt < 2; ++rt)
                        #pragma unroll
                        for (int reg = 0; reg < 4; ++reg)
                            p[rt][reg] += __shfl_xor(p[rt][reg], msk, 64);
                float* sp = s_part + (m & 1) * 256;
                if (c == 0) {
                    #pragma unroll
                    for (int rt = 0; rt < 2; ++rt)
                        #pragma unroll
                        for (int reg = 0; reg < 4; ++reg)
                            sp[w * 32 + rt * 16 + g * 4 + reg] = p[rt][reg];
                }
                __syncthreads();                 // s_part[m&1] complete
                if (tid < BN) {
                    float s = 0.f;
                    #pragma unroll
                    for (int ww = 0; ww < 8; ++ww) s += sp[ww * 32 + tid];
                    sm[m] = s + cm[m];
                }
                // no second barrier: next m writes the OTHER s_part buffer
            }

            if (tid < BN) {
                float e0 = __expf(sm[0] * SCALE), e1 = __expf(sm[1] * SCALE),
                      e2 = __expf(sm[2] * SCALE), e3 = __expf(sm[3] * SCALE);
                float iz = 1.f / (e0 + e1 + e2 + e3);
                f32x4 wv = {e0 * iz, e1 * iz, e2 * iz, e3 * iz};
                wlds[tid] = wv;
                if (row0 + tid < NTOK)
                    *(f32x4*)(out + WOFF + (size_t)(row0 + tid) * 4) = wv;
            }
            __syncthreads();                     // wlds ready

            // ---- inline fuse: this tile's lat rows are L2/L3-hot from lv ----
            // d_ws path (defer==0): all tiles fuse here (no overlap w/ scratch)
            // fallback (defer==1): tiles >= TAIL_T defer to phase 3
            if (!defer || t < TAIL_T) {
                #pragma unroll 2
                for (int i = 0; i < 8; ++i) {
                    int f4 = i * 512 + tid, r = f4 >> 7, c4 = f4 & 127;
                    if (row0 + r < NTOK) {
                        f32x4 w4 = wlds[r];
                        const float* lp = lat + (size_t)(row0 + r) * NMOD * DDIM + c4 * 4;
                        f32x4 acc = {0.f, 0.f, 0.f, 0.f};
                        #pragma unroll
                        for (int m = 0; m < NMOD; ++m)
                            acc += w4[m] * *(const f32x4*)(lp + m * DDIM);
                        __builtin_nontemporal_store(acc,
                            (f32x4*)(out + (size_t)(row0 + r) * DDIM + c4 * 4));
                    }
                }
            }
        }
    }

    // ===== phase 3 (fallback only): fuse the deferred tail tiles =====
    if (defer) {
        gg.sync();   // weights visible; out-tail scratch now dead
        const long t4 = (long)(NTOK - TAIL_T * BN) * 128;   // 153,600
        for (long idx = (long)bid * 512 + tid; idx < t4;
             idx += (long)ngrid * 512) {
            const int row = TAIL_T * BN + (int)(idx >> 7), c4 = (int)(idx & 127);
            f32x4 w4 = *(const f32x4*)(out + WOFF + (size_t)row * 4);
            f32x4 acc = {0.f, 0.f, 0.f, 0.f};
            #pragma unroll
            for (int m = 0; m < NMOD; ++m) {
                f32x4 v = __builtin_nontemporal_load(
                    (const f32x4*)(lat + ((size_t)row * NMOD + m) * DDIM + c4 * 4));
                acc += w4[m] * v;
            }
            __builtin_nontemporal_store(acc,
                (f32x4*)(out + (size_t)row * DDIM + c4 * 4));
        }
    }
}

extern "C" void kernel_launch(void* const* d_in, const int* in_sizes, int n_in,
                              void* d_out, int out_size, void* d_ws, size_t ws_size,
                              hipStream_t stream)
{
    const float* gnn = (const float*)d_in[0];   // [N, D]
    const float* lat = (const float*)d_in[1];   // [N, M, D]
    const float* Wq  = (const float*)d_in[2];   // [D, D]
    const float* bq  = (const float*)d_in[3];   // [D]
    const float* Wk  = (const float*)d_in[4];   // [M, D, D]
    const float* bk  = (const float*)d_in[5];   // [M, D]
    float* out = (float*)d_out;                 // fused [N,D] ++ weights [N,M]

    // scratch: prefer d_ws (single grid.sync); fallback to tail of fused region
    const size_t need = (size_t)(GFLOATS + 2048 + 2048 + 4 + 32 + 16) * 4;
    float* sc;
    int defer;
    if (ws_size >= need) { sc = (float*)d_ws;      defer = 0; }
    else                 { sc = out + 25000000;    defer = 1; }

    int maxb = 0;
    hipError_t oe = hipOccupancyMaxActiveBlocksPerMultiprocessor(
        &maxb, mono_kernel, 512, 0);
    if (oe != hipSuccess || maxb < 1) maxb = 1;
    if (maxb > 4) maxb = 4;
    const int ngrid = 256 * maxb;

    void* args[] = { (void*)&gnn, (void*)&lat, (void*)&Wq, (void*)&bq,
                     (void*)&Wk, (void*)&bk, (void*)&out, (void*)&sc,
                     (void*)&defer };
    hipLaunchCooperativeKernel((const void*)mono_kernel, dim3(ngrid), dim3(512),
                               args, 0, stream);
}

// Round 16
// 517.220 us; speedup vs baseline: 1.6884x; 1.1797x over previous
//
#include <hip/hip_runtime.h>
#include <hip/hip_cooperative_groups.h>

namespace cg = cooperative_groups;

// ---------------------------------------------------------------------------
// InterpretableFusion v16 — ONE cooperative kernel, ONE grid.sync (d_ws path).
//   scores[n,m] = ( x.(G_m l) + x.v_m + l.u_m + c_m )/sqrt(D)
//   y = x Gt_m^T via MFMA (packed-G b-fragments, X tile staged once),
//   s = (y+u).l, softmax -> weights; fused inline per tile (lat L2-hot).
// v15 -> v16: __launch_bounds__(512,2). Same 2 blocks/CU (LDS caps at 4,
// VGPR caps at 2 -> 16 waves/CU unchanged) but arch-VGPR cap 64 -> 128:
//  (a) kills the ~125MB of spill traffic that the 64-cap forced (WRITE 232MB
//      vs 107MB ideal in v13..v15),
//  (b) affords prefetching the 16 lv scalars BEFORE the k-loop so their
//      ~900cy cold-HBM latency hides under the ~1600cy MFMA k-loop
//      (v13 had moved them after the k-loop to fit 64 regs — serializing
//      HBM latency with compute, the dominant per-tile cost),
//  (c) k-loop unroll 2 -> 4 for deeper b-load pipelining (L2 latency).
// ---------------------------------------------------------------------------

typedef __bf16 bf16x8 __attribute__((ext_vector_type(8)));
typedef __bf16 bf16x4 __attribute__((ext_vector_type(4)));
typedef float  f32x4  __attribute__((ext_vector_type(4)));

#define NTOK 50000
#define DDIM 512
#define NMOD 4
#define BN   32
#define NBLK ((NTOK + BN - 1) / BN)        // 1563
#define WOFF ((size_t)NTOK * DDIM)         // weights region (float offset)
#define GFLOATS 524288                     // packed G: 2MB = 524288 floats
#define TAIL_T 1525                        // fallback: tiles >= this defer fuse
#define SCALE 0.044194173824159216f        // 1/sqrt(512)

// X-tile swizzle: row stride 1024B; XOR byte bits 4-6 with row&7 (guide §6 G4)
#define SWZ(r, b) ((((r) * 1024) + (b)) ^ (((r) & 7) << 4))

__global__ __launch_bounds__(512, 2) void mono_kernel(
    const float* __restrict__ gnn, const float* __restrict__ lat,
    const float* __restrict__ Wq, const float* __restrict__ bq,
    const float* __restrict__ Wk, const float* __restrict__ bk,
    float* __restrict__ out, float* __restrict__ sc, int defer)
{
    __shared__ __align__(16) char smem[35328];  // 32K tile + s_part dbuf + wlds
    const int tid = threadIdx.x;
    const int bid = blockIdx.x;
    const int ngrid = gridDim.x;
    cg::grid_group gg = cg::this_grid();

    float* uP = sc + GFLOATS;          // u[m][d']  (4*512)
    float* vP = uP + 2048;             // v[m][d]
    float* cP = vP + 2048;             // c[m]
    float* fP = cP + 4;                // 32 bias-nonzero flags

    // ===== phase 1: Gt[m][e][d] = sum_r Wk[m][r][e]*Wq[r][d], PACKED store ===
    {
        float* ldsA = (float*)smem;            // [r][64 e-cols of Wk_m]
        float* ldsB = (float*)(smem + 16384);  // [r][32 d-cols of Wq]
        for (int gb = bid; gb < 512; gb += ngrid) {
            const int m = gb >> 7, ib = gb & 127, eblk = ib >> 4, dpb = ib & 15;
            const int el = tid >> 3, c8 = tid & 7;
            f32x4 ac = {0.f, 0.f, 0.f, 0.f};
            for (int r0 = 0; r0 < DDIM; r0 += 64) {
                __syncthreads();
                #pragma unroll
                for (int it = 0; it < 2; ++it) {
                    int idx = it * 512 + tid, r = idx >> 4, c4 = idx & 15;
                    *(f32x4*)&ldsA[r * 64 + c4 * 4] =
                        *(const f32x4*)&Wk[((size_t)m * DDIM + r0 + r) * DDIM + eblk * 64 + c4 * 4];
                }
                {
                    int r = tid >> 3, c4 = tid & 7;
                    *(f32x4*)&ldsB[r * 32 + c4 * 4] =
                        *(const f32x4*)&Wq[(size_t)(r0 + r) * DDIM + dpb * 32 + c4 * 4];
                }
                __syncthreads();
                for (int r = 0; r < 64; ++r) {
                    float wk = ldsA[r * 64 + el];
                    ac += wk * *(const f32x4*)&ldsB[r * 32 + c8 * 4];
                }
            }
            // packed store: element (e,d): kk=d>>5, g=(d>>3)&3, eta=e>>4,
            // lane = g*16+(e&15); 16B-unit = ((m*16+kk)*32+eta)*64+lane
            __bf16* Gw = (__bf16*)sc;
            const int eta = eblk * 4 + (el >> 4);
            const int lam = (c8 >> 1) * 16 + (el & 15);
            size_t abf = ((((size_t)m * 16 + dpb) * 32 + eta) * 64 + lam) * 8
                         + (c8 & 1) * 4;
            bf16x4 o;
            o[0] = (__bf16)ac[0]; o[1] = (__bf16)ac[1];
            o[2] = (__bf16)ac[2]; o[3] = (__bf16)ac[3];
            *(bf16x4*)(Gw + abf) = o;
        }

        if (bid < 32) {                        // u, v, c + bias flags
            __syncthreads();                   // own block's LDS reads done
            float* up = (float*)smem;          // [4][64]
            float* vp = (float*)smem + 256;    // [4][64]
            const int m2 = bid >> 3, dc = bid & 7;
            if (tid < 256) {
                const int dl2 = tid & 63, eg = tid >> 6;
                const int d = dc * 64 + dl2;
                float us = 0.f, vs = 0.f;
                #pragma unroll 4
                for (int e = eg * 128; e < eg * 128 + 128; ++e) {
                    us += Wk[((size_t)m2 * DDIM + e) * DDIM + d] * bq[e];
                    vs += Wq[(size_t)e * DDIM + d] * bk[m2 * DDIM + e];
                }
                up[eg * 64 + dl2] = us; vp[eg * 64 + dl2] = vs;
            }
            __syncthreads();
            if (tid < 64) {
                const int d = dc * 64 + tid;
                float uu = up[tid] + up[64+tid] + up[128+tid] + up[192+tid];
                float vv = vp[tid] + vp[64+tid] + vp[128+tid] + vp[192+tid];
                uP[m2 * DDIM + d] = uu;
                vP[m2 * DDIM + d] = vv;
                float cp = 0.f;
                if (dc == 0) {
                    #pragma unroll
                    for (int i = 0; i < 8; ++i)
                        cp += bq[tid * 8 + i] * bk[m2 * DDIM + tid * 8 + i];
                    #pragma unroll
                    for (int msk = 1; msk < 64; msk <<= 1)
                        cp += __shfl_xor(cp, msk, 64);
                    if (tid == 0) cP[m2] = cp;
                }
                unsigned long long anyb =
                    __ballot((uu != 0.f) || (vv != 0.f) || (cp != 0.f));
                if (tid == 0) fP[bid] = anyb ? 1.f : 0.f;   // always written
            }
        }
    }
    gg.sync();   // packed Gt/u/v/c/flags visible device-wide (THE one sync)

    // ===== phase 2: scores -> softmax -> weights -> INLINE fuse =====
    {
        __bf16* tile  = (__bf16*)smem;             // 32 KiB: X tile
        float* s_part = (float*)(smem + 32768);    // 2 x [8][32] double buffer
        f32x4* wlds   = (f32x4*)(smem + 34816);    // [32] normalized weights
        const __bf16* Gp = (const __bf16*)sc;
        const int lane = tid & 63, w = tid >> 6;
        const int g = (lane >> 4) & 3, c = lane & 15;

        bool bias = false;
        for (int i2 = 0; i2 < 32; ++i2) bias |= (fP[i2] != 0.f);
        float cm[4];
        #pragma unroll
        for (int m = 0; m < 4; ++m) cm[m] = cP[m];

        for (int t = bid; t < NBLK; t += ngrid) {
            const int row0 = t * BN;
            const int vrows = (NTOK - row0 < BN) ? (NTOK - row0) : BN;

            {   // stage X once per tile
                const float* src = gnn + (size_t)row0 * DDIM;
                #pragma unroll
                for (int i = 0; i < 8; ++i) {
                    int f4 = i * 512 + tid, r = f4 >> 7, c4 = f4 & 127;
                    f32x4 v = (r < vrows)
                        ? __builtin_nontemporal_load(
                              (const f32x4*)(src + (size_t)r * DDIM + c4 * 4))
                        : (f32x4){0.f, 0.f, 0.f, 0.f};
                    bf16x4 o;
                    o[0] = (__bf16)v[0]; o[1] = (__bf16)v[1];
                    o[2] = (__bf16)v[2]; o[3] = (__bf16)v[3];
                    *(bf16x4*)((char*)tile + SWZ(r, c4 * 8)) = o;
                }
            }
            __syncthreads();

            float sm[4];   // per-row scores, meaningful for tid < BN
            for (int m = 0; m < NMOD; ++m) {
                float p[2][4];
                if (bias) {
                    float v4[4];
                    #pragma unroll
                    for (int j = 0; j < 4; ++j)
                        v4[j] = vP[m * DDIM + w * 64 + j * 16 + c];
                    #pragma unroll
                    for (int rt = 0; rt < 2; ++rt)
                        #pragma unroll
                        for (int reg = 0; reg < 4; ++reg) {
                            int r = rt * 16 + g * 4 + reg;
                            float tacc = 0.f;
                            #pragma unroll
                            for (int j = 0; j < 4; ++j) {
                                int col = w * 64 + j * 16 + c;
                                float xv = (float)*(const __bf16*)((const char*)tile +
                                                                   SWZ(r, col * 2));
                                tacc += xv * v4[j];
                            }
                            p[rt][reg] = tacc;
                        }
                } else {
                    #pragma unroll
                    for (int rt = 0; rt < 2; ++rt)
                        #pragma unroll
                        for (int reg = 0; reg < 4; ++reg)
                            p[rt][reg] = 0.f;
                }

                const __bf16* gm = Gp + (size_t)m * 262144;   // 512KB per m
                #pragma unroll
                for (int jh = 0; jh < 2; ++jh) {
                    // PREFETCH lv for both jj of this jh (16 regs): their
                    // ~900cy HBM latency hides under the MFMA k-loop below.
                    float lv[2][2][4];
                    #pragma unroll
                    for (int jj = 0; jj < 2; ++jj) {
                        const int e = w * 64 + (jh * 2 + jj) * 16 + c;
                        #pragma unroll
                        for (int rt = 0; rt < 2; ++rt)
                            #pragma unroll
                            for (int reg = 0; reg < 4; ++reg) {
                                int row = row0 + rt * 16 + g * 4 + reg;
                                lv[jj][rt][reg] = (row < NTOK)
                                    ? lat[((size_t)row * NMOD + m) * DDIM + e]
                                    : 0.f;
                            }
                    }

                    f32x4 kacc[2][2];
                    #pragma unroll
                    for (int rt = 0; rt < 2; ++rt) {
                        kacc[rt][0] = (f32x4){0.f, 0.f, 0.f, 0.f};
                        kacc[rt][1] = (f32x4){0.f, 0.f, 0.f, 0.f};
                    }
                    // packed b-loads: one contiguous 1KB wave read per fragment
                    const __bf16* gpk = gm + (w * 4 + jh * 2) * 512 + lane * 8;
                    #pragma unroll 4
                    for (int kk = 0; kk < 16; ++kk) {
                        bf16x8 b0 = *(const bf16x8*)(gpk + kk * 16384);
                        bf16x8 b1 = *(const bf16x8*)(gpk + kk * 16384 + 512);
                        bf16x8 a[2];
                        const int kb = kk * 64 + g * 16;
                        a[0] = *(const bf16x8*)((const char*)tile + SWZ(c, kb));
                        a[1] = *(const bf16x8*)((const char*)tile + SWZ(16 + c, kb));
                        kacc[0][0] = __builtin_amdgcn_mfma_f32_16x16x32_bf16(
                            a[0], b0, kacc[0][0], 0, 0, 0);
                        kacc[1][0] = __builtin_amdgcn_mfma_f32_16x16x32_bf16(
                            a[1], b0, kacc[1][0], 0, 0, 0);
                        kacc[0][1] = __builtin_amdgcn_mfma_f32_16x16x32_bf16(
                            a[0], b1, kacc[0][1], 0, 0, 0);
                        kacc[1][1] = __builtin_amdgcn_mfma_f32_16x16x32_bf16(
                            a[1], b1, kacc[1][1], 0, 0, 0);
                    }

                    // dot with prefetched lv
                    #pragma unroll
                    for (int jj = 0; jj < 2; ++jj) {
                        const int e = w * 64 + (jh * 2 + jj) * 16 + c;
                        float uj = bias ? uP[m * DDIM + e] : 0.f;
                        #pragma unroll
                        for (int rt = 0; rt < 2; ++rt)
                            #pragma unroll
                            for (int reg = 0; reg < 4; ++reg)
                                p[rt][reg] += lv[jj][rt][reg] * (kacc[rt][jj][reg] + uj);
                    }
                    __builtin_amdgcn_sched_barrier(0);
                }

                // reduce over 16 c-lanes, then across 8 waves via LDS (dbuf)
                #pragma unroll
                for (int msk = 1; msk < 16; msk <<= 1)
                    #pragma unroll
                    for (int rt = 0; rt < 2; ++rt)
                        #pragma unroll
                        for (int reg = 0; reg < 4; ++reg)
                            p[rt][reg] += __shfl_xor(p[rt][reg], msk, 64);
                float* sp = s_part + (m & 1) * 256;
                if (c == 0) {
                    #pragma unroll
                    for (int rt = 0; rt < 2; ++rt)
                        #pragma unroll
                        for (int reg = 0; reg < 4; ++reg)
                            sp[w * 32 + rt * 16 + g * 4 + reg] = p[rt][reg];
                }
                __syncthreads();                 // s_part[m&1] complete
                if (tid < BN) {
                    float s = 0.f;
                    #pragma unroll
                    for (int ww = 0; ww < 8; ++ww) s += sp[ww * 32 + tid];
                    sm[m] = s + cm[m];
                }
                // no second barrier: next m writes the OTHER s_part buffer
            }

            if (tid < BN) {
                float e0 = __expf(sm[0] * SCALE), e1 = __expf(sm[1] * SCALE),
                      e2 = __expf(sm[2] * SCALE), e3 = __expf(sm[3] * SCALE);
                float iz = 1.f / (e0 + e1 + e2 + e3);
                f32x4 wv = {e0 * iz, e1 * iz, e2 * iz, e3 * iz};
                wlds[tid] = wv;
                if (row0 + tid < NTOK)
                    *(f32x4*)(out + WOFF + (size_t)(row0 + tid) * 4) = wv;
            }
            __syncthreads();                     // wlds ready

            // ---- inline fuse: this tile's lat rows are L2/L3-hot from lv ----
            if (!defer || t < TAIL_T) {
                #pragma unroll 2
                for (int i = 0; i < 8; ++i) {
                    int f4 = i * 512 + tid, r = f4 >> 7, c4 = f4 & 127;
                    if (row0 + r < NTOK) {
                        f32x4 w4 = wlds[r];
                        const float* lp = lat + (size_t)(row0 + r) * NMOD * DDIM + c4 * 4;
                        f32x4 acc = {0.f, 0.f, 0.f, 0.f};
                        #pragma unroll
                        for (int m = 0; m < NMOD; ++m)
                            acc += w4[m] * *(const f32x4*)(lp + m * DDIM);
                        __builtin_nontemporal_store(acc,
                            (f32x4*)(out + (size_t)(row0 + r) * DDIM + c4 * 4));
                    }
                }
            }
        }
    }

    // ===== phase 3 (fallback only): fuse the deferred tail tiles =====
    if (defer) {
        gg.sync();   // weights visible; out-tail scratch now dead
        const long t4 = (long)(NTOK - TAIL_T * BN) * 128;   // 153,600
        for (long idx = (long)bid * 512 + tid; idx < t4;
             idx += (long)ngrid * 512) {
            const int row = TAIL_T * BN + (int)(idx >> 7), c4 = (int)(idx & 127);
            f32x4 w4 = *(const f32x4*)(out + WOFF + (size_t)row * 4);
            f32x4 acc = {0.f, 0.f, 0.f, 0.f};
            #pragma unroll
            for (int m = 0; m < NMOD; ++m) {
                f32x4 v = __builtin_nontemporal_load(
                    (const f32x4*)(lat + ((size_t)row * NMOD + m) * DDIM + c4 * 4));
                acc += w4[m] * v;
            }
            __builtin_nontemporal_store(acc,
                (f32x4*)(out + (size_t)row * DDIM + c4 * 4));
        }
    }
}

extern "C" void kernel_launch(void* const* d_in, const int* in_sizes, int n_in,
                              void* d_out, int out_size, void* d_ws, size_t ws_size,
                              hipStream_t stream)
{
    const float* gnn = (const float*)d_in[0];   // [N, D]
    const float* lat = (const float*)d_in[1];   // [N, M, D]
    const float* Wq  = (const float*)d_in[2];   // [D, D]
    const float* bq  = (const float*)d_in[3];   // [D]
    const float* Wk  = (const float*)d_in[4];   // [M, D, D]
    const float* bk  = (const float*)d_in[5];   // [M, D]
    float* out = (float*)d_out;                 // fused [N,D] ++ weights [N,M]

    // scratch: prefer d_ws (single grid.sync); fallback to tail of fused region
    const size_t need = (size_t)(GFLOATS + 2048 + 2048 + 4 + 32 + 16) * 4;
    float* sc;
    int defer;
    if (ws_size >= need) { sc = (float*)d_ws;      defer = 0; }
    else                 { sc = out + 25000000;    defer = 1; }

    int maxb = 0;
    hipError_t oe = hipOccupancyMaxActiveBlocksPerMultiprocessor(
        &maxb, mono_kernel, 512, 0);
    if (oe != hipSuccess || maxb < 1) maxb = 1;
    if (maxb > 4) maxb = 4;
    const int ngrid = 256 * maxb;

    void* args[] = { (void*)&gnn, (void*)&lat, (void*)&Wq, (void*)&bq,
                     (void*)&Wk, (void*)&bk, (void*)&out, (void*)&sc,
                     (void*)&defer };
    hipLaunchCooperativeKernel((const void*)mono_kernel, dim3(ngrid), dim3(512),
                               args, 0, stream);
}